// Round 1
// baseline (487.164 us; speedup 1.0000x reference)
//
#include <hip/hip_runtime.h>

// VQSpeaker: obs[32,2048,128] -> 3-layer MLP -> x[65536,64] -> VQ argmin over
// codebook[2048,64] -> (msg = codebook[idx], idx, cmt_loss).
// All fp32 (no fp32-input MFMA on CDNA4; argmin precision forbids bf16 here).
//
// d_out layout (float32): msg[4194304] | idx[65536] (written as float) | loss[1]

#define NPTS    65536
#define IN_DIM  128
#define HID     64
#define OUT_DIM 64
#define CB_N    2048
#define MSG_ELEMS (NPTS * OUT_DIM)        // 4194304
#define LOSS_SCALE (1.0f / 4194304.0f)

__global__ void zero_loss_kernel(float* __restrict__ loss) { *loss = 0.0f; }

// ---------------- MLP: 64 points/block, 256 threads, 4pts x 4outs/thread ----
__global__ __launch_bounds__(256) void mlp_kernel(
    const float* __restrict__ obs,
    const float* __restrict__ W1, const float* __restrict__ b1,
    const float* __restrict__ W2, const float* __restrict__ b2,
    const float* __restrict__ W3, const float* __restrict__ b3,
    float* __restrict__ xout)
{
    // wbuf: W1[128*64] for layer1; then W2/W3[64*64] in [0,4096) + h2[64][68] at +4096.
    __shared__ float wbuf[8448];
    __shared__ float h1_s[64 * 68];   // h1 (stride 68 = 4 mod 32 -> <=2-way banks); later x staging
    __shared__ float bias_s[64];

    const int t = threadIdx.x;
    const long base = (long)blockIdx.x * 64;
    const int pt = t & 15, jt = t >> 4;   // pt: point group (16), jt: out group (16)

    // ---- load W1 (natural [k][j]) + b1 ----
    #pragma unroll
    for (int m = 0; m < 32; ++m) wbuf[t + 256 * m] = W1[t + 256 * m];
    if (t < 64) bias_s[t] = b1[t];
    __syncthreads();

    float acc[4][4];
    #pragma unroll
    for (int i = 0; i < 4; ++i)
        #pragma unroll
        for (int j = 0; j < 4; ++j) acc[i][j] = 0.0f;

    const float* obs_rows[4];
    #pragma unroll
    for (int i = 0; i < 4; ++i) obs_rows[i] = obs + (base + pt + 16 * i) * IN_DIM;

    // layer 1: obs from global (16-lane broadcast per row, L1-served), W1 from LDS
    for (int k = 0; k < 128; k += 4) {
        float4 ov[4];
        #pragma unroll
        for (int i = 0; i < 4; ++i) ov[i] = *(const float4*)(obs_rows[i] + k);
        #pragma unroll
        for (int jj = 0; jj < 4; ++jj) {
            const int j = jt + 16 * jj;
            const float w0 = wbuf[(k + 0) * 64 + j];
            const float w1v = wbuf[(k + 1) * 64 + j];
            const float w2v = wbuf[(k + 2) * 64 + j];
            const float w3v = wbuf[(k + 3) * 64 + j];
            #pragma unroll
            for (int i = 0; i < 4; ++i)
                acc[i][jj] += ov[i].x * w0 + ov[i].y * w1v + ov[i].z * w2v + ov[i].w * w3v;
        }
    }
    #pragma unroll
    for (int i = 0; i < 4; ++i)
        #pragma unroll
        for (int jj = 0; jj < 4; ++jj) {
            const float v = acc[i][jj] + bias_s[jt + 16 * jj];
            h1_s[(pt + 16 * i) * 68 + jt + 16 * jj] = v > 0.0f ? v : 0.0f;
        }
    __syncthreads();

    // ---- layer 2 ----
    #pragma unroll
    for (int m = 0; m < 16; ++m) wbuf[t + 256 * m] = W2[t + 256 * m];
    if (t < 64) bias_s[t] = b2[t];
    __syncthreads();

    float* h2_s = wbuf + 4096;   // disjoint from W2 region [0,4096)
    #pragma unroll
    for (int i = 0; i < 4; ++i)
        #pragma unroll
        for (int j = 0; j < 4; ++j) acc[i][j] = 0.0f;
    for (int k = 0; k < 64; k += 4) {
        float4 hv[4];
        #pragma unroll
        for (int i = 0; i < 4; ++i) hv[i] = *(const float4*)&h1_s[(pt + 16 * i) * 68 + k];
        #pragma unroll
        for (int jj = 0; jj < 4; ++jj) {
            const int j = jt + 16 * jj;
            const float w0 = wbuf[(k + 0) * 64 + j];
            const float w1v = wbuf[(k + 1) * 64 + j];
            const float w2v = wbuf[(k + 2) * 64 + j];
            const float w3v = wbuf[(k + 3) * 64 + j];
            #pragma unroll
            for (int i = 0; i < 4; ++i)
                acc[i][jj] += hv[i].x * w0 + hv[i].y * w1v + hv[i].z * w2v + hv[i].w * w3v;
        }
    }
    #pragma unroll
    for (int i = 0; i < 4; ++i)
        #pragma unroll
        for (int jj = 0; jj < 4; ++jj) {
            const float v = acc[i][jj] + bias_s[jt + 16 * jj];
            h2_s[(pt + 16 * i) * 68 + jt + 16 * jj] = v > 0.0f ? v : 0.0f;
        }
    __syncthreads();

    // ---- layer 3 (no relu) ----
    #pragma unroll
    for (int m = 0; m < 16; ++m) wbuf[t + 256 * m] = W3[t + 256 * m];
    if (t < 64) bias_s[t] = b3[t];
    __syncthreads();

    #pragma unroll
    for (int i = 0; i < 4; ++i)
        #pragma unroll
        for (int j = 0; j < 4; ++j) acc[i][j] = 0.0f;
    for (int k = 0; k < 64; k += 4) {
        float4 hv[4];
        #pragma unroll
        for (int i = 0; i < 4; ++i) hv[i] = *(const float4*)&h2_s[(pt + 16 * i) * 68 + k];
        #pragma unroll
        for (int jj = 0; jj < 4; ++jj) {
            const int j = jt + 16 * jj;
            const float w0 = wbuf[(k + 0) * 64 + j];
            const float w1v = wbuf[(k + 1) * 64 + j];
            const float w2v = wbuf[(k + 2) * 64 + j];
            const float w3v = wbuf[(k + 3) * 64 + j];
            #pragma unroll
            for (int i = 0; i < 4; ++i)
                acc[i][jj] += hv[i].x * w0 + hv[i].y * w1v + hv[i].z * w2v + hv[i].w * w3v;
        }
    }
    // x -> h1_s (h1 dead after layer 2; last reads fenced by the W3-load barrier)
    #pragma unroll
    for (int i = 0; i < 4; ++i)
        #pragma unroll
        for (int jj = 0; jj < 4; ++jj)
            h1_s[(pt + 16 * i) * 68 + jt + 16 * jj] = acc[i][jj] + bias_s[jt + 16 * jj];
    __syncthreads();

    // coalesced store of x tile (64*64 floats = 1024 float4)
    float4* og = (float4*)(xout + base * OUT_DIM);
    #pragma unroll
    for (int m = 0; m < 4; ++m) {
        const int v = t + 256 * m;
        const int p = v >> 4, k4 = v & 15;
        og[v] = *(const float4*)&h1_s[p * 68 + k4 * 4];
    }
}

// ---------------- VQ: 64 points/block, 256 threads, 16 tiles of 128 codes ----
// dist ordering via d = |c|^2 - 2*x.c (x^2 is a per-point constant shift).
// Tie-break = lowest code index (matches np.argmin first-occurrence).
__global__ __launch_bounds__(256) void vq_kernel(
    const float* __restrict__ codebook,
    float* __restrict__ msg,        // in: x (staged by mlp), out: quantize
    float* __restrict__ idx_out,    // written as float values
    float* __restrict__ loss_out)
{
    __shared__ float x_s[64 * 68];
    __shared__ float c_s[128 * 68];   // codebook tile; reused for argmin reduction
    __shared__ float e2_s[128];       // |c|^2 per tile; reused as idx_s[64]
    __shared__ float wred[4];

    const int t = threadIdx.x;
    const long base = (long)blockIdx.x * 64;
    float* xg = msg + base * OUT_DIM;

    // load x tile (1024 float4, coalesced)
    #pragma unroll
    for (int m = 0; m < 4; ++m) {
        const int v = t + 256 * m;
        const int p = v >> 4, k4 = v & 15;
        *(float4*)&x_s[p * 68 + k4 * 4] = ((const float4*)xg)[v];
    }
    __syncthreads();

    const int pt = t & 15, ct = t >> 4;   // pt: point group, ct: code group
    float bestd[4];
    int   besti[4];
    #pragma unroll
    for (int i = 0; i < 4; ++i) { bestd[i] = 3.4e38f; besti[i] = 0; }

    for (int tile = 0; tile < 16; ++tile) {
        // load codebook tile 128x64 (2048 float4, coalesced; L2-resident)
        const float4* cg = (const float4*)(codebook + (long)tile * 128 * OUT_DIM);
        #pragma unroll
        for (int m = 0; m < 8; ++m) {
            const int v = t + 256 * m;
            const int c = v >> 4, k4 = v & 15;
            *(float4*)&c_s[c * 68 + k4 * 4] = cg[v];
        }
        __syncthreads();

        if (t < 128) {
            float s = 0.0f;
            for (int k = 0; k < 64; k += 4) {
                const float4 cv = *(const float4*)&c_s[t * 68 + k];
                s += cv.x * cv.x + cv.y * cv.y + cv.z * cv.z + cv.w * cv.w;
            }
            e2_s[t] = s;
        }
        __syncthreads();

        float acc[4][8];
        #pragma unroll
        for (int i = 0; i < 4; ++i)
            #pragma unroll
            for (int j = 0; j < 8; ++j) acc[i][j] = 0.0f;

        // 12 ds_read_b128 : 128 v_fmac per k-chunk -> VALU-bound
        for (int k = 0; k < 64; k += 4) {
            float4 xv[4];
            #pragma unroll
            for (int i = 0; i < 4; ++i) xv[i] = *(const float4*)&x_s[(pt + 16 * i) * 68 + k];
            #pragma unroll
            for (int j = 0; j < 8; ++j) {
                const float4 cv = *(const float4*)&c_s[(ct + 16 * j) * 68 + k];
                #pragma unroll
                for (int i = 0; i < 4; ++i)
                    acc[i][j] += xv[i].x * cv.x + xv[i].y * cv.y + xv[i].z * cv.z + xv[i].w * cv.w;
            }
        }
        #pragma unroll
        for (int j = 0; j < 8; ++j) {
            const int code = tile * 128 + ct + 16 * j;   // strictly increasing visit order
            const float e2 = e2_s[ct + 16 * j];
            #pragma unroll
            for (int i = 0; i < 4; ++i) {
                const float d = e2 - 2.0f * acc[i][j];
                if (d < bestd[i]) { bestd[i] = d; besti[i] = code; }
            }
        }
        __syncthreads();   // before next tile overwrites c_s / e2_s
    }

    // cross-thread argmin reduce over the 16 code-groups per point
    float* red_d = c_s;                // [64][17] (stride 17: odd -> conflict-free)
    float* red_i = c_s + 64 * 17;
    #pragma unroll
    for (int i = 0; i < 4; ++i) {
        const int p = pt + 16 * i;
        red_d[p * 17 + ct] = bestd[i];
        red_i[p * 17 + ct] = (float)besti[i];
    }
    __syncthreads();

    if (t < 64) {
        float bd = 3.4e38f; int bi = 1 << 30;
        #pragma unroll
        for (int c = 0; c < 16; ++c) {
            const float d = red_d[t * 17 + c];
            const int ii = (int)red_i[t * 17 + c];
            if (d < bd || (d == bd && ii < bi)) { bd = d; bi = ii; }
        }
        e2_s[t] = (float)bi;                   // idx_s
        idx_out[base + t] = (float)bi;         // idx as float32 values
    }
    __syncthreads();

    // gather codebook[idx] (coalesced per row), write msg, accumulate loss
    float lsum = 0.0f;
    #pragma unroll
    for (int m = 0; m < 4; ++m) {
        const int v = t + 256 * m;
        const int p = v >> 4, k4 = v & 15;
        const int code = (int)e2_s[p];
        const float4 q = ((const float4*)(codebook + (long)code * OUT_DIM))[k4];
        const float4 xv = *(const float4*)&x_s[p * 68 + k4 * 4];
        const float dx = q.x - xv.x, dy = q.y - xv.y, dz = q.z - xv.z, dw = q.w - xv.w;
        lsum += dx * dx + dy * dy + dz * dz + dw * dw;
        ((float4*)xg)[v] = q;
    }
    #pragma unroll
    for (int off = 32; off > 0; off >>= 1) lsum += __shfl_down(lsum, off, 64);
    if ((t & 63) == 0) wred[t >> 6] = lsum;
    __syncthreads();
    if (t == 0)
        atomicAdd(loss_out, (wred[0] + wred[1] + wred[2] + wred[3]) * LOSS_SCALE);
}

extern "C" void kernel_launch(void* const* d_in, const int* in_sizes, int n_in,
                              void* d_out, int out_size, void* d_ws, size_t ws_size,
                              hipStream_t stream) {
    const float* obs = (const float*)d_in[0];
    const float* W1  = (const float*)d_in[1];
    const float* b1  = (const float*)d_in[2];
    const float* W2  = (const float*)d_in[3];
    const float* b2  = (const float*)d_in[4];
    const float* W3  = (const float*)d_in[5];
    const float* b3  = (const float*)d_in[6];
    const float* cb  = (const float*)d_in[7];

    float* out  = (float*)d_out;
    float* msg  = out;                        // also x staging
    float* idxf = out + MSG_ELEMS;
    float* loss = out + MSG_ELEMS + NPTS;

    zero_loss_kernel<<<1, 1, 0, stream>>>(loss);
    mlp_kernel<<<NPTS / 64, 256, 0, stream>>>(obs, W1, b1, W2, b2, W3, b3, msg);
    vq_kernel<<<NPTS / 64, 256, 0, stream>>>(cb, msg, idxf, loss);
}

// Round 2
// 396.833 us; speedup vs baseline: 1.2276x; 1.2276x over previous
//
#include <hip/hip_runtime.h>

// VQSpeaker: obs[32,2048,128] -> 3-layer MLP -> x[65536,64] -> VQ argmin over
// codebook[2048,64] -> (msg = codebook[idx], idx, cmt_loss).
// All fp32 (no fp32-input MFMA on CDNA4; argmin exactness forbids bf16 here).
//
// d_out layout (float32): msg[4194304] | idx[65536] (written as float) | loss[1]
// d_ws: e2[2048] = |codebook row|^2
//
// VQ strategy (round 2): lane-per-point. Each lane holds its point's x in 64
// VGPRs; code index is wave-uniform (readfirstlane) so codebook reads promote
// to s_load and feed v_fmac's scalar operand -> no LDS in the inner loop.

#define NPTS    65536
#define IN_DIM  128
#define HID     64
#define OUT_DIM 64
#define CB_N    2048
#define MSG_ELEMS (NPTS * OUT_DIM)        // 4194304
#define LOSS_SCALE (1.0f / 4194304.0f)
#define VQ_WAVES 8                        // 512 threads, 8 waves x 256 codes

__global__ void zero_loss_kernel(float* __restrict__ loss) { *loss = 0.0f; }

__global__ __launch_bounds__(256) void e2_kernel(
    const float* __restrict__ codebook, float* __restrict__ e2)
{
    const int c = blockIdx.x * 256 + threadIdx.x;
    const float4* row = (const float4*)(codebook + (long)c * OUT_DIM);
    float s = 0.0f;
    #pragma unroll
    for (int m = 0; m < 16; ++m) {
        const float4 v = row[m];
        s += v.x * v.x + v.y * v.y + v.z * v.z + v.w * v.w;
    }
    e2[c] = s;
}

// ---------------- MLP: 64 points/block, 256 threads, 4pts x 4outs/thread ----
__global__ __launch_bounds__(256) void mlp_kernel(
    const float* __restrict__ obs,
    const float* __restrict__ W1, const float* __restrict__ b1,
    const float* __restrict__ W2, const float* __restrict__ b2,
    const float* __restrict__ W3, const float* __restrict__ b3,
    float* __restrict__ xout)
{
    __shared__ float wbuf[8448];
    __shared__ float h1_s[64 * 68];   // stride 68 -> <=2-way banks (free)
    __shared__ float bias_s[64];

    const int t = threadIdx.x;
    const long base = (long)blockIdx.x * 64;
    const int pt = t & 15, jt = t >> 4;

    #pragma unroll
    for (int m = 0; m < 32; ++m) wbuf[t + 256 * m] = W1[t + 256 * m];
    if (t < 64) bias_s[t] = b1[t];
    __syncthreads();

    float acc[4][4];
    #pragma unroll
    for (int i = 0; i < 4; ++i)
        #pragma unroll
        for (int j = 0; j < 4; ++j) acc[i][j] = 0.0f;

    const float* obs_rows[4];
    #pragma unroll
    for (int i = 0; i < 4; ++i) obs_rows[i] = obs + (base + pt + 16 * i) * IN_DIM;

    for (int k = 0; k < 128; k += 4) {
        float4 ov[4];
        #pragma unroll
        for (int i = 0; i < 4; ++i) ov[i] = *(const float4*)(obs_rows[i] + k);
        #pragma unroll
        for (int jj = 0; jj < 4; ++jj) {
            const int j = jt + 16 * jj;
            const float w0 = wbuf[(k + 0) * 64 + j];
            const float w1v = wbuf[(k + 1) * 64 + j];
            const float w2v = wbuf[(k + 2) * 64 + j];
            const float w3v = wbuf[(k + 3) * 64 + j];
            #pragma unroll
            for (int i = 0; i < 4; ++i) {
                acc[i][jj] = fmaf(ov[i].x, w0, acc[i][jj]);
                acc[i][jj] = fmaf(ov[i].y, w1v, acc[i][jj]);
                acc[i][jj] = fmaf(ov[i].z, w2v, acc[i][jj]);
                acc[i][jj] = fmaf(ov[i].w, w3v, acc[i][jj]);
            }
        }
    }
    #pragma unroll
    for (int i = 0; i < 4; ++i)
        #pragma unroll
        for (int jj = 0; jj < 4; ++jj) {
            const float v = acc[i][jj] + bias_s[jt + 16 * jj];
            h1_s[(pt + 16 * i) * 68 + jt + 16 * jj] = v > 0.0f ? v : 0.0f;
        }
    __syncthreads();

    #pragma unroll
    for (int m = 0; m < 16; ++m) wbuf[t + 256 * m] = W2[t + 256 * m];
    if (t < 64) bias_s[t] = b2[t];
    __syncthreads();

    float* h2_s = wbuf + 4096;
    #pragma unroll
    for (int i = 0; i < 4; ++i)
        #pragma unroll
        for (int j = 0; j < 4; ++j) acc[i][j] = 0.0f;
    for (int k = 0; k < 64; k += 4) {
        float4 hv[4];
        #pragma unroll
        for (int i = 0; i < 4; ++i) hv[i] = *(const float4*)&h1_s[(pt + 16 * i) * 68 + k];
        #pragma unroll
        for (int jj = 0; jj < 4; ++jj) {
            const int j = jt + 16 * jj;
            const float w0 = wbuf[(k + 0) * 64 + j];
            const float w1v = wbuf[(k + 1) * 64 + j];
            const float w2v = wbuf[(k + 2) * 64 + j];
            const float w3v = wbuf[(k + 3) * 64 + j];
            #pragma unroll
            for (int i = 0; i < 4; ++i) {
                acc[i][jj] = fmaf(hv[i].x, w0, acc[i][jj]);
                acc[i][jj] = fmaf(hv[i].y, w1v, acc[i][jj]);
                acc[i][jj] = fmaf(hv[i].z, w2v, acc[i][jj]);
                acc[i][jj] = fmaf(hv[i].w, w3v, acc[i][jj]);
            }
        }
    }
    #pragma unroll
    for (int i = 0; i < 4; ++i)
        #pragma unroll
        for (int jj = 0; jj < 4; ++jj) {
            const float v = acc[i][jj] + bias_s[jt + 16 * jj];
            h2_s[(pt + 16 * i) * 68 + jt + 16 * jj] = v > 0.0f ? v : 0.0f;
        }
    __syncthreads();

    #pragma unroll
    for (int m = 0; m < 16; ++m) wbuf[t + 256 * m] = W3[t + 256 * m];
    if (t < 64) bias_s[t] = b3[t];
    __syncthreads();

    #pragma unroll
    for (int i = 0; i < 4; ++i)
        #pragma unroll
        for (int j = 0; j < 4; ++j) acc[i][j] = 0.0f;
    for (int k = 0; k < 64; k += 4) {
        float4 hv[4];
        #pragma unroll
        for (int i = 0; i < 4; ++i) hv[i] = *(const float4*)&h2_s[(pt + 16 * i) * 68 + k];
        #pragma unroll
        for (int jj = 0; jj < 4; ++jj) {
            const int j = jt + 16 * jj;
            const float w0 = wbuf[(k + 0) * 64 + j];
            const float w1v = wbuf[(k + 1) * 64 + j];
            const float w2v = wbuf[(k + 2) * 64 + j];
            const float w3v = wbuf[(k + 3) * 64 + j];
            #pragma unroll
            for (int i = 0; i < 4; ++i) {
                acc[i][jj] = fmaf(hv[i].x, w0, acc[i][jj]);
                acc[i][jj] = fmaf(hv[i].y, w1v, acc[i][jj]);
                acc[i][jj] = fmaf(hv[i].z, w2v, acc[i][jj]);
                acc[i][jj] = fmaf(hv[i].w, w3v, acc[i][jj]);
            }
        }
    }
    #pragma unroll
    for (int i = 0; i < 4; ++i)
        #pragma unroll
        for (int jj = 0; jj < 4; ++jj)
            h1_s[(pt + 16 * i) * 68 + jt + 16 * jj] = acc[i][jj] + bias_s[jt + 16 * jj];
    __syncthreads();

    float4* og = (float4*)(xout + base * OUT_DIM);
    #pragma unroll
    for (int m = 0; m < 4; ++m) {
        const int v = t + 256 * m;
        const int p = v >> 4, k4 = v & 15;
        og[v] = *(const float4*)&h1_s[p * 68 + k4 * 4];
    }
}

// ---------------- VQ scan: 512 thr = 8 waves; wave = 64 lane-points, 256 codes
__global__ __launch_bounds__(512) void vq_scan(
    const float* __restrict__ codebook,
    const float* __restrict__ e2,
    float* __restrict__ msg,        // in: x (staged by mlp), out: quantize
    float* __restrict__ idx_out,    // written as float values
    float* __restrict__ loss_out)
{
    __shared__ float red_d[VQ_WAVES][64];
    __shared__ int   red_i[VQ_WAVES][64];

    const int t = threadIdx.x;
    const int lane = t & 63;
    const int w = __builtin_amdgcn_readfirstlane(t >> 6);   // provably uniform
    const long base = (long)blockIdx.x * 64;

    // x for this lane's point: 64 floats in VGPRs
    const float4* xrow = (const float4*)(msg + (base + lane) * OUT_DIM);
    float4 xv[16];
    #pragma unroll
    for (int m = 0; m < 16; ++m) xv[m] = xrow[m];

    float bd = 3.4e38f;
    int   bi = 0;
    const int code0 = w * (CB_N / VQ_WAVES);

    for (int cc = 0; cc < CB_N / VQ_WAVES; ++cc) {
        const int code = code0 + cc;                         // uniform
        const float* __restrict__ c = codebook + (long)code * OUT_DIM;  // -> s_load
        float a0 = 0.0f, a1 = 0.0f;                          // 2 chains hide fmac latency
        #pragma unroll
        for (int m = 0; m < 16; ++m) {
            a0 = fmaf(xv[m].x, c[4 * m + 0], a0);
            a1 = fmaf(xv[m].y, c[4 * m + 1], a1);
            a0 = fmaf(xv[m].z, c[4 * m + 2], a0);
            a1 = fmaf(xv[m].w, c[4 * m + 3], a1);
        }
        const float d = fmaf(-2.0f, a0 + a1, e2[code]);      // ordering == |c|^2-2x.c
        if (d < bd) { bd = d; bi = code; }                   // strict <: first occurrence
    }
    red_d[w][lane] = bd;
    red_i[w][lane] = bi;
    __syncthreads();

    if (w == 0) {
        float fbd = red_d[0][lane];
        int   fbi = red_i[0][lane];
        #pragma unroll
        for (int ww = 1; ww < VQ_WAVES; ++ww) {              // ascending code chunks:
            const float d = red_d[ww][lane];                 // strict < keeps lowest idx
            const int  ii = red_i[ww][lane];
            if (d < fbd) { fbd = d; fbi = ii; }
        }
        idx_out[base + lane] = (float)fbi;

        // gather q, loss, overwrite msg row (x still live in xv regs)
        const float4* q4 = (const float4*)(codebook + (long)fbi * OUT_DIM);
        float4* og = (float4*)(msg + (base + lane) * OUT_DIM);
        float lsum = 0.0f;
        #pragma unroll
        for (int m = 0; m < 16; ++m) {
            const float4 q = q4[m];
            const float dx = q.x - xv[m].x, dy = q.y - xv[m].y;
            const float dz = q.z - xv[m].z, dw2 = q.w - xv[m].w;
            lsum += dx * dx + dy * dy + dz * dz + dw2 * dw2;
            og[m] = q;
        }
        #pragma unroll
        for (int off = 32; off > 0; off >>= 1) lsum += __shfl_down(lsum, off, 64);
        if (lane == 0) atomicAdd(loss_out, lsum * LOSS_SCALE);
    }
}

extern "C" void kernel_launch(void* const* d_in, const int* in_sizes, int n_in,
                              void* d_out, int out_size, void* d_ws, size_t ws_size,
                              hipStream_t stream) {
    const float* obs = (const float*)d_in[0];
    const float* W1  = (const float*)d_in[1];
    const float* b1  = (const float*)d_in[2];
    const float* W2  = (const float*)d_in[3];
    const float* b2  = (const float*)d_in[4];
    const float* W3  = (const float*)d_in[5];
    const float* b3  = (const float*)d_in[6];
    const float* cb  = (const float*)d_in[7];

    float* out  = (float*)d_out;
    float* msg  = out;                        // also x staging
    float* idxf = out + MSG_ELEMS;
    float* loss = out + MSG_ELEMS + NPTS;
    float* e2   = (float*)d_ws;               // 2048 floats

    zero_loss_kernel<<<1, 1, 0, stream>>>(loss);
    e2_kernel<<<CB_N / 256, 256, 0, stream>>>(cb, e2);
    mlp_kernel<<<NPTS / 64, 256, 0, stream>>>(obs, W1, b1, W2, b2, W3, b3, msg);
    vq_scan<<<NPTS / 64, 512, 0, stream>>>(cb, e2, msg, idxf, loss);
}

// Round 3
// 307.644 us; speedup vs baseline: 1.5835x; 1.2899x over previous
//
#include <hip/hip_runtime.h>

// VQSpeaker: obs[32,2048,128] -> 3-layer MLP -> x[65536,64] -> VQ argmin over
// codebook[2048,64] -> (msg = codebook[idx], idx, cmt_loss).
//
// Round 3: VQ distance matmul on the MATRIX pipe via bf16-split MFMA
// (x_hi*c_hi + x_lo*c_hi + x_hi*c_lo, fp32 acc), with margin screening +
// exact fp32 rescore so argmin matches the fp32 reference semantics.
//
// d_out layout (float32): msg[4194304] | idx[65536] (as float) | loss[1]
// d_ws: e2[2048] f32 | cb_hi_perm[2048*64] bf16 | cb_lo_perm[2048*64] bf16

#define NPTS    65536
#define IN_DIM  128
#define HID     64
#define OUT_DIM 64
#define CB_N    2048
#define MSG_ELEMS (NPTS * OUT_DIM)
#define LOSS_SCALE (1.0f / 4194304.0f)
#define MARG 0.5f          // >> 2*eps of the bf16-split (~1e-2): sound screening
#define CAND_CAP 512

typedef __attribute__((ext_vector_type(8))) short short8;
typedef __attribute__((ext_vector_type(4))) float f32x4;

__device__ __forceinline__ unsigned short f2bf(float f) {
    unsigned u = __float_as_uint(f);
    u += 0x7FFF + ((u >> 16) & 1);          // RN-even to bf16
    return (unsigned short)(u >> 16);
}
__device__ __forceinline__ float bf2f(unsigned short h) {
    return __uint_as_float((unsigned)h << 16);
}

__global__ void zero_loss_kernel(float* __restrict__ loss) { *loss = 0.0f; }

__global__ __launch_bounds__(256) void e2_kernel(
    const float* __restrict__ codebook, float* __restrict__ e2)
{
    const int c = blockIdx.x * 256 + threadIdx.x;
    const float4* row = (const float4*)(codebook + (long)c * OUT_DIM);
    float s = 0.0f;
    #pragma unroll
    for (int m = 0; m < 16; ++m) {
        const float4 v = row[m];
        s += v.x * v.x + v.y * v.y + v.z * v.z + v.w * v.w;
    }
    e2[c] = s;
}

// Permute codebook into MFMA B-fragment order, split hi/lo bf16.
// For 16x16x32 bf16: B[k][n], n=lane&15, k=(lane>>4)*8+j. Element for
// (tile,half,lane,j) = cb[tile*16+(lane&15)][half*32+(lane>>4)*8+j].
// dst index = ((tile*2+half)*64 + lane)*8 + j  -> frag load = lane*16B, coalesced.
__global__ __launch_bounds__(256) void prep_kernel(
    const float* __restrict__ cb,
    unsigned short* __restrict__ cbh, unsigned short* __restrict__ cbl)
{
    const int id = blockIdx.x * 256 + threadIdx.x;  // 0..4095: (code n, half h)
    const int n = id >> 1, h = id & 1;
    const int t = n >> 4, l15 = n & 15;
    const float* src = cb + (long)n * OUT_DIM + h * 32;
    #pragma unroll
    for (int quad = 0; quad < 4; ++quad) {
        short8 hi, lo;
        #pragma unroll
        for (int j = 0; j < 8; ++j) {
            const float f = src[quad * 8 + j];
            const unsigned short hb = f2bf(f);
            hi[j] = (short)hb;
            lo[j] = (short)f2bf(f - bf2f(hb));
        }
        const long dst = ((long)(t * 2 + h) * 64 + quad * 16 + l15) * 8;
        *(short8*)(cbh + dst) = hi;
        *(short8*)(cbl + dst) = lo;
    }
}

// ---------------- MLP: unchanged from round 2 ----------------
__global__ __launch_bounds__(256) void mlp_kernel(
    const float* __restrict__ obs,
    const float* __restrict__ W1, const float* __restrict__ b1,
    const float* __restrict__ W2, const float* __restrict__ b2,
    const float* __restrict__ W3, const float* __restrict__ b3,
    float* __restrict__ xout)
{
    __shared__ float wbuf[8448];
    __shared__ float h1_s[64 * 68];
    __shared__ float bias_s[64];

    const int t = threadIdx.x;
    const long base = (long)blockIdx.x * 64;
    const int pt = t & 15, jt = t >> 4;

    #pragma unroll
    for (int m = 0; m < 32; ++m) wbuf[t + 256 * m] = W1[t + 256 * m];
    if (t < 64) bias_s[t] = b1[t];
    __syncthreads();

    float acc[4][4];
    #pragma unroll
    for (int i = 0; i < 4; ++i)
        #pragma unroll
        for (int j = 0; j < 4; ++j) acc[i][j] = 0.0f;

    const float* obs_rows[4];
    #pragma unroll
    for (int i = 0; i < 4; ++i) obs_rows[i] = obs + (base + pt + 16 * i) * IN_DIM;

    for (int k = 0; k < 128; k += 4) {
        float4 ov[4];
        #pragma unroll
        for (int i = 0; i < 4; ++i) ov[i] = *(const float4*)(obs_rows[i] + k);
        #pragma unroll
        for (int jj = 0; jj < 4; ++jj) {
            const int j = jt + 16 * jj;
            const float w0 = wbuf[(k + 0) * 64 + j];
            const float w1v = wbuf[(k + 1) * 64 + j];
            const float w2v = wbuf[(k + 2) * 64 + j];
            const float w3v = wbuf[(k + 3) * 64 + j];
            #pragma unroll
            for (int i = 0; i < 4; ++i) {
                acc[i][jj] = fmaf(ov[i].x, w0, acc[i][jj]);
                acc[i][jj] = fmaf(ov[i].y, w1v, acc[i][jj]);
                acc[i][jj] = fmaf(ov[i].z, w2v, acc[i][jj]);
                acc[i][jj] = fmaf(ov[i].w, w3v, acc[i][jj]);
            }
        }
    }
    #pragma unroll
    for (int i = 0; i < 4; ++i)
        #pragma unroll
        for (int jj = 0; jj < 4; ++jj) {
            const float v = acc[i][jj] + bias_s[jt + 16 * jj];
            h1_s[(pt + 16 * i) * 68 + jt + 16 * jj] = v > 0.0f ? v : 0.0f;
        }
    __syncthreads();

    #pragma unroll
    for (int m = 0; m < 16; ++m) wbuf[t + 256 * m] = W2[t + 256 * m];
    if (t < 64) bias_s[t] = b2[t];
    __syncthreads();

    float* h2_s = wbuf + 4096;
    #pragma unroll
    for (int i = 0; i < 4; ++i)
        #pragma unroll
        for (int j = 0; j < 4; ++j) acc[i][j] = 0.0f;
    for (int k = 0; k < 64; k += 4) {
        float4 hv[4];
        #pragma unroll
        for (int i = 0; i < 4; ++i) hv[i] = *(const float4*)&h1_s[(pt + 16 * i) * 68 + k];
        #pragma unroll
        for (int jj = 0; jj < 4; ++jj) {
            const int j = jt + 16 * jj;
            const float w0 = wbuf[(k + 0) * 64 + j];
            const float w1v = wbuf[(k + 1) * 64 + j];
            const float w2v = wbuf[(k + 2) * 64 + j];
            const float w3v = wbuf[(k + 3) * 64 + j];
            #pragma unroll
            for (int i = 0; i < 4; ++i) {
                acc[i][jj] = fmaf(hv[i].x, w0, acc[i][jj]);
                acc[i][jj] = fmaf(hv[i].y, w1v, acc[i][jj]);
                acc[i][jj] = fmaf(hv[i].z, w2v, acc[i][jj]);
                acc[i][jj] = fmaf(hv[i].w, w3v, acc[i][jj]);
            }
        }
    }
    #pragma unroll
    for (int i = 0; i < 4; ++i)
        #pragma unroll
        for (int jj = 0; jj < 4; ++jj) {
            const float v = acc[i][jj] + bias_s[jt + 16 * jj];
            h2_s[(pt + 16 * i) * 68 + jt + 16 * jj] = v > 0.0f ? v : 0.0f;
        }
    __syncthreads();

    #pragma unroll
    for (int m = 0; m < 16; ++m) wbuf[t + 256 * m] = W3[t + 256 * m];
    if (t < 64) bias_s[t] = b3[t];
    __syncthreads();

    #pragma unroll
    for (int i = 0; i < 4; ++i)
        #pragma unroll
        for (int j = 0; j < 4; ++j) acc[i][j] = 0.0f;
    for (int k = 0; k < 64; k += 4) {
        float4 hv[4];
        #pragma unroll
        for (int i = 0; i < 4; ++i) hv[i] = *(const float4*)&h2_s[(pt + 16 * i) * 68 + k];
        #pragma unroll
        for (int jj = 0; jj < 4; ++jj) {
            const int j = jt + 16 * jj;
            const float w0 = wbuf[(k + 0) * 64 + j];
            const float w1v = wbuf[(k + 1) * 64 + j];
            const float w2v = wbuf[(k + 2) * 64 + j];
            const float w3v = wbuf[(k + 3) * 64 + j];
            #pragma unroll
            for (int i = 0; i < 4; ++i) {
                acc[i][jj] = fmaf(hv[i].x, w0, acc[i][jj]);
                acc[i][jj] = fmaf(hv[i].y, w1v, acc[i][jj]);
                acc[i][jj] = fmaf(hv[i].z, w2v, acc[i][jj]);
                acc[i][jj] = fmaf(hv[i].w, w3v, acc[i][jj]);
            }
        }
    }
    #pragma unroll
    for (int i = 0; i < 4; ++i)
        #pragma unroll
        for (int jj = 0; jj < 4; ++jj)
            h1_s[(pt + 16 * i) * 68 + jt + 16 * jj] = acc[i][jj] + bias_s[jt + 16 * jj];
    __syncthreads();

    float4* og = (float4*)(xout + base * OUT_DIM);
    #pragma unroll
    for (int m = 0; m < 4; ++m) {
        const int v = t + 256 * m;
        const int p = v >> 4, k4 = v & 15;
        og[v] = *(const float4*)&h1_s[p * 68 + k4 * 4];
    }
}

// exact fp32 distance update (same numerics as round-2's passing kernel)
__device__ __forceinline__ void exact_upd(
    const float* __restrict__ xr, const float* __restrict__ cb,
    const float* __restrict__ e2, int n, float& bd, int& bi)
{
    const float4* xp = (const float4*)xr;
    const float4* cp = (const float4*)(cb + (long)n * OUT_DIM);
    float a0 = 0.0f, a1 = 0.0f;
    #pragma unroll
    for (int m = 0; m < 16; ++m) {
        const float4 xv = xp[m], cv = cp[m];
        a0 = fmaf(xv.x, cv.x, a0); a1 = fmaf(xv.y, cv.y, a1);
        a0 = fmaf(xv.z, cv.z, a0); a1 = fmaf(xv.w, cv.w, a1);
    }
    const float ex = fmaf(-2.0f, a0 + a1, e2[n]);
    if (ex < bd || (ex == bd && n < bi)) { bd = ex; bi = n; }
}

// ---------------- VQ via MFMA: 256 thr = 4 waves; wave = 16 pts x all codes --
__global__ __launch_bounds__(256) void vq_mfma(
    const float* __restrict__ cb,
    const unsigned short* __restrict__ cbhp,
    const unsigned short* __restrict__ cblp,
    const float* __restrict__ e2,
    float* __restrict__ msg,        // in: x, out: quantize
    float* __restrict__ idx_out,
    float* __restrict__ loss_out)
{
    __shared__ float best_d_s[4][16][16];   // [wave][pt][col]
    __shared__ int   best_i_s[4][16][16];
    __shared__ int   cand_pc[CAND_CAP];     // (p_local<<16) | code
    __shared__ float cand_d[CAND_CAP];
    __shared__ int   cand_cnt;
    __shared__ int   idx_sh[64];
    __shared__ float wred[4];

    const int t = threadIdx.x, lane = t & 63, w = t >> 6;
    const int m = lane & 15, quad = lane >> 4;
    const long base = (long)blockIdx.x * 64;

    if (t == 0) cand_cnt = 0;

    // A-frags: x[point = w*16 + m][k = quad*8 + j], halves k0=0/32. Built once.
    const float* xrow = msg + (base + w * 16 + m) * OUT_DIM;
    short8 a0h, a0l, a1h, a1l;
    {
        const float4 xa = *(const float4*)(xrow + quad * 8);
        const float4 xb = *(const float4*)(xrow + quad * 8 + 4);
        const float4 xc = *(const float4*)(xrow + 32 + quad * 8);
        const float4 xd = *(const float4*)(xrow + 32 + quad * 8 + 4);
        const float x0[8] = {xa.x, xa.y, xa.z, xa.w, xb.x, xb.y, xb.z, xb.w};
        const float x1[8] = {xc.x, xc.y, xc.z, xc.w, xd.x, xd.y, xd.z, xd.w};
        #pragma unroll
        for (int j = 0; j < 8; ++j) {
            unsigned short hb = f2bf(x0[j]);
            a0h[j] = (short)hb; a0l[j] = (short)f2bf(x0[j] - bf2f(hb));
            hb = f2bf(x1[j]);
            a1h[j] = (short)hb; a1l[j] = (short)f2bf(x1[j] - bf2f(hb));
        }
    }
    __syncthreads();   // cand_cnt visible

    float bd[4] = {3.4e38f, 3.4e38f, 3.4e38f, 3.4e38f};
    int   bi[4] = {0, 0, 0, 0};

    // register double-buffered B-frags
    long toff = (long)lane * 8;
    short8 bh0 = *(const short8*)(cbhp + toff);
    short8 bh1 = *(const short8*)(cbhp + toff + 512);
    short8 bl0 = *(const short8*)(cblp + toff);
    short8 bl1 = *(const short8*)(cblp + toff + 512);

    for (int tile = 0; tile < 128; ++tile) {
        const int nt = (tile + 1 < 128) ? tile + 1 : 127;
        const long noff = (long)nt * 1024 + (long)lane * 8;
        const short8 nh0 = *(const short8*)(cbhp + noff);
        const short8 nh1 = *(const short8*)(cbhp + noff + 512);
        const short8 nl0 = *(const short8*)(cblp + noff);
        const short8 nl1 = *(const short8*)(cblp + noff + 512);
        const float e2v = e2[tile * 16 + m];

        f32x4 acc0 = {0.0f, 0.0f, 0.0f, 0.0f};
        f32x4 acc1 = {0.0f, 0.0f, 0.0f, 0.0f};
        acc0 = __builtin_amdgcn_mfma_f32_16x16x32_bf16(a0h, bh0, acc0, 0, 0, 0);
        acc1 = __builtin_amdgcn_mfma_f32_16x16x32_bf16(a1h, bh1, acc1, 0, 0, 0);
        acc0 = __builtin_amdgcn_mfma_f32_16x16x32_bf16(a0l, bh0, acc0, 0, 0, 0);
        acc1 = __builtin_amdgcn_mfma_f32_16x16x32_bf16(a1l, bh1, acc1, 0, 0, 0);
        acc0 = __builtin_amdgcn_mfma_f32_16x16x32_bf16(a0h, bl0, acc0, 0, 0, 0);
        acc1 = __builtin_amdgcn_mfma_f32_16x16x32_bf16(a1h, bl1, acc1, 0, 0, 0);

        const int code = tile * 16 + m;
        #pragma unroll
        for (int r = 0; r < 4; ++r) {
            const float d = fmaf(-2.0f, acc0[r] + acc1[r], e2v);
            if (d < bd[r]) {
                if (bd[r] < d + MARG) {                 // near-tie supersession
                    const int slot = atomicAdd(&cand_cnt, 1);
                    if (slot < CAND_CAP) {
                        cand_pc[slot] = ((w * 16 + quad * 4 + r) << 16) | bi[r];
                        cand_d[slot] = bd[r];
                    }
                }
                bd[r] = d; bi[r] = code;
            } else if (d < bd[r] + MARG) {              // within margin of run-min
                const int slot = atomicAdd(&cand_cnt, 1);
                if (slot < CAND_CAP) {
                    cand_pc[slot] = ((w * 16 + quad * 4 + r) << 16) | code;
                    cand_d[slot] = d;
                }
            }
        }
        bh0 = nh0; bh1 = nh1; bl0 = nl0; bl1 = nl1;
    }

    // publish per-slot bests: point row = quad*4 + r, col = m
    #pragma unroll
    for (int r = 0; r < 4; ++r) {
        best_d_s[w][quad * 4 + r][m] = bd[r];
        best_i_s[w][quad * 4 + r][m] = bi[r];
    }
    __syncthreads();

    // exact-rescore stage: one thread per point
    if (t < 64) {
        const int p = t, ww = p >> 4, pi = p & 15;
        float dmin = 3.4e38f;
        #pragma unroll
        for (int c = 0; c < 16; ++c) dmin = fminf(dmin, best_d_s[ww][pi][c]);
        const float thr = dmin + MARG;

        float fbd = 3.4e38f; int fbi = 1 << 30;
        const float* xr = msg + (base + p) * OUT_DIM;   // still x
        #pragma unroll
        for (int c = 0; c < 16; ++c)
            if (best_d_s[ww][pi][c] <= thr)
                exact_upd(xr, cb, e2, best_i_s[ww][pi][c], fbd, fbi);
        const int L = min(cand_cnt, CAND_CAP);
        for (int l = 0; l < L; ++l) {
            const int pc = cand_pc[l];
            if ((pc >> 16) == p && cand_d[l] <= thr)
                exact_upd(xr, cb, e2, pc & 0xFFFF, fbd, fbi);
        }
        idx_sh[p] = fbi;
        idx_out[base + p] = (float)fbi;
    }
    __syncthreads();

    // gather q, write msg, accumulate loss (read-x / write-q same thread+addr)
    float lsum = 0.0f;
    float4* xg = (float4*)(msg + base * OUT_DIM);
    #pragma unroll
    for (int mm = 0; mm < 4; ++mm) {
        const int v = t + 256 * mm;
        const int p = v >> 4, k4 = v & 15;
        const int code = idx_sh[p];
        const float4 q = ((const float4*)(cb + (long)code * OUT_DIM))[k4];
        const float4 xv = xg[v];
        const float dx = q.x - xv.x, dy = q.y - xv.y;
        const float dz = q.z - xv.z, dw2 = q.w - xv.w;
        lsum += dx * dx + dy * dy + dz * dz + dw2 * dw2;
        xg[v] = q;
    }
    #pragma unroll
    for (int off = 32; off > 0; off >>= 1) lsum += __shfl_down(lsum, off, 64);
    if (lane == 0) wred[w] = lsum;
    __syncthreads();
    if (t == 0)
        atomicAdd(loss_out, (wred[0] + wred[1] + wred[2] + wred[3]) * LOSS_SCALE);
}

extern "C" void kernel_launch(void* const* d_in, const int* in_sizes, int n_in,
                              void* d_out, int out_size, void* d_ws, size_t ws_size,
                              hipStream_t stream) {
    const float* obs = (const float*)d_in[0];
    const float* W1  = (const float*)d_in[1];
    const float* b1  = (const float*)d_in[2];
    const float* W2  = (const float*)d_in[3];
    const float* b2  = (const float*)d_in[4];
    const float* W3  = (const float*)d_in[5];
    const float* b3  = (const float*)d_in[6];
    const float* cb  = (const float*)d_in[7];

    float* out  = (float*)d_out;
    float* msg  = out;                        // also x staging
    float* idxf = out + MSG_ELEMS;
    float* loss = out + MSG_ELEMS + NPTS;

    float*          e2  = (float*)d_ws;                       // 8 KB
    unsigned short* cbh = (unsigned short*)((char*)d_ws + 8192);
    unsigned short* cbl = cbh + CB_N * OUT_DIM;               // +256 KB each

    zero_loss_kernel<<<1, 1, 0, stream>>>(loss);
    e2_kernel<<<CB_N / 256, 256, 0, stream>>>(cb, e2);
    prep_kernel<<<16, 256, 0, stream>>>(cb, cbh, cbl);
    mlp_kernel<<<NPTS / 64, 256, 0, stream>>>(obs, W1, b1, W2, b2, W3, b3, msg);
    vq_mfma<<<NPTS / 64, 256, 0, stream>>>(cb, cbh, cbl, e2, msg, idxf, loss);
}